// Round 2
// baseline (128.848 us; speedup 1.0000x reference)
//
#include <hip/hip_runtime.h>
#include <math.h>

#define HW    9216      // 96*96
#define NPIX  18432     // B*HW
#define NKEY  8192
#define NC    32        // key chunks
#define KPC   (NKEY/NC) // 256 keys per chunk
#define QPT   8         // queries per thread in k2

// ws layout (float units)
#define OFF_Q    0                      // [NPIX][4]
#define OFF_KV   (OFF_Q + NPIX*4)       // [NKEY][6]
#define OFF_EEHS (OFF_KV + NKEY*6)      // [NPIX][8]  : EE0..2,S | HH0..2,pad
#define OFF_MM   (OFF_EEHS + NPIX*8)    // [288][2]   : per-block S min,max
#define OFF_PART (OFF_MM + 576)         // [NC][NPIX][4] : s, sv0, sv1, sv2

__device__ __forceinline__ float gelu_tanh(float x){
    float u = 0.7978845608028654f*(x + 0.044715f*x*x*x);
    return 0.5f*x*(1.0f + tanhf(u));
}

__global__ __launch_bounds__(64) void k1_prep(
    const float* __restrict__ front, const float* __restrict__ back,
    const float* __restrict__ bg,
    const float* __restrict__ mi_w1, const float* __restrict__ mi_b1,
    const float* __restrict__ mi_w2, const float* __restrict__ mi_b2,
    const float* __restrict__ q_w,  const float* __restrict__ k_w,
    const float* __restrict__ v_w,
    const float* __restrict__ n1_g, const float* __restrict__ n1_b,
    const float* __restrict__ e_w,  const float* __restrict__ e_b,
    const float* __restrict__ f_w,  const float* __restrict__ f_b,
    const float* __restrict__ g_w,  const float* __restrict__ g_b,
    const float* __restrict__ h_w,  const float* __restrict__ h_b,
    float* __restrict__ ws)
{
    float* ws_q    = ws + OFF_Q;
    float* ws_kv   = ws + OFF_KV;
    float* ws_eehs = ws + OFF_EEHS;
    float* ws_mm   = ws + OFF_MM;

    int tid = threadIdx.x;
    int pix = blockIdx.x*64 + tid;      // 0..18431

    // ---------- keys: k,v from codebook ----------
    if (pix < NKEY){
        float c0 = bg[pix], c1 = bg[NKEY+pix], c2 = bg[2*NKEY+pix];
        #pragma unroll
        for (int i=0;i<3;i++){
            ws_kv[pix*6+i]   = k_w[i*3+0]*c0 + k_w[i*3+1]*c1 + k_w[i*3+2]*c2;
            ws_kv[pix*6+3+i] = v_w[i*3+0]*c0 + v_w[i*3+1]*c1 + v_w[i*3+2]*c2;
        }
    }

    int b   = (pix >= HW) ? 1 : 0;
    int pos = pix - b*HW;
    int y   = pos / 96;
    int x   = pos - y*96;
    const float* fbase = front + b*3*HW;
    const float* bbase = back  + b*3*HW;

    // ---------- 7x7 zero-padded box sums ----------
    float s1f[3]={0,0,0}, s2f[3]={0,0,0}, s1b[3]={0,0,0}, s2b[3]={0,0,0};
    for (int dy=-3; dy<=3; ++dy){
        int yy = y+dy;
        if (yy < 0 || yy >= 96) continue;
        for (int dx=-3; dx<=3; ++dx){
            int xx = x+dx;
            if (xx < 0 || xx >= 96) continue;
            int off = yy*96+xx;
            #pragma unroll
            for (int c=0;c<3;c++){
                float fv = fbase[c*HW+off];
                float bv = bbase[c*HW+off];
                s1f[c]+=fv; s2f[c]+=fv*fv;
                s1b[c]+=bv; s2b[c]+=bv*bv;
            }
        }
    }

    float xnf[3], adain[3], bn[3], bval[3];
    #pragma unroll
    for (int c=0;c<3;c++){
        float mf = s1f[c]*(1.0f/49.0f);
        float vf = (s2f[c] - s1f[c]*s1f[c]*(1.0f/49.0f))*(1.0f/48.0f);
        float fv = fbase[c*HW+pos];
        xnf[c] = (fv - mf)/(sqrtf(vf)+1e-8f);

        float mb = s1b[c]*(1.0f/49.0f);
        float vb = (s2b[c] - s1b[c]*s1b[c]*(1.0f/49.0f))*(1.0f/48.0f);
        float bb = bbase[c*HW+pos];
        bval[c]  = bb;
        float stdb = sqrtf(vb);
        adain[c] = xnf[c]*stdb + mb;         // no eps on y_std
        bn[c]    = (bb - mb)/(stdb + 1e-8f);
    }

    float EE[3], FF[3], GG[3], HHv[3];
    #pragma unroll
    for (int i=0;i<3;i++){
        EE[i]  = e_w[i*3+0]*adain[0] + e_w[i*3+1]*adain[1] + e_w[i*3+2]*adain[2] + e_b[i];
        FF[i]  = f_w[i*3+0]*xnf[0]   + f_w[i*3+1]*xnf[1]   + f_w[i*3+2]*xnf[2]   + f_b[i];
        GG[i]  = g_w[i*3+0]*bn[0]    + g_w[i*3+1]*bn[1]    + g_w[i*3+2]*bn[2]    + g_b[i];
        HHv[i] = h_w[i*3+0]*bval[0]  + h_w[i*3+1]*bval[1]  + h_w[i*3+2]*bval[2]  + h_b[i];
    }
    float num = FF[0]*GG[0]+FF[1]*GG[1]+FF[2]*GG[2];
    float fn  = sqrtf(FF[0]*FF[0]+FF[1]*FF[1]+FF[2]*FF[2]);
    float gn  = sqrtf(GG[0]*GG[0]+GG[1]*GG[1]+GG[2]*GG[2]);
    float S   = num/(fn*gn);

    float4* eehs4 = (float4*)ws_eehs;
    eehs4[pix*2+0] = make_float4(EE[0],EE[1],EE[2],S);
    eehs4[pix*2+1] = make_float4(HHv[0],HHv[1],HHv[2],0.0f);

    // ---------- per-block S min/max via wave shuffle (block == 1 wave) ----------
    float mn = S, mx = S;
    #pragma unroll
    for (int off=32; off>0; off>>=1){
        mn = fminf(mn, __shfl_xor(mn, off));
        mx = fmaxf(mx, __shfl_xor(mx, off));
    }
    if (tid==0){ ws_mm[blockIdx.x*2+0]=mn; ws_mm[blockIdx.x*2+1]=mx; }

    // ---------- token q : mlp_in -> ln -> q_w, pre-scaled by scale*log2e ----------
    float xt0 = fbase[0*HW+pos], xt1 = fbase[1*HW+pos], xt2 = fbase[2*HW+pos];
    float h6[6];
    #pragma unroll
    for (int i=0;i<6;i++){
        float a = mi_w1[i*3+0]*xt0 + mi_w1[i*3+1]*xt1 + mi_w1[i*3+2]*xt2 + mi_b1[i];
        h6[i] = gelu_tanh(a);
    }
    float x2[3];
    #pragma unroll
    for (int i=0;i<3;i++){
        float a = mi_b2[i];
        #pragma unroll
        for (int k=0;k<6;k++) a += mi_w2[i*6+k]*h6[k];
        x2[i]=a;
    }
    float m  = (x2[0]+x2[1]+x2[2])*(1.0f/3.0f);
    float d0 = x2[0]-m, d1 = x2[1]-m, d2 = x2[2]-m;
    float var = (d0*d0+d1*d1+d2*d2)*(1.0f/3.0f);
    float inv = 1.0f/sqrtf(var+1e-5f);
    float xn0 = d0*inv*n1_g[0]+n1_b[0];
    float xn1 = d1*inv*n1_g[1]+n1_b[1];
    float xn2 = d2*inv*n1_g[2]+n1_b[2];
    const float qs = 0.5773502691896258f * 1.4426950408889634f; // d^-0.5 * log2(e)
    float4 qv;
    qv.x = (q_w[0]*xn0 + q_w[1]*xn1 + q_w[2]*xn2)*qs;
    qv.y = (q_w[3]*xn0 + q_w[4]*xn1 + q_w[5]*xn2)*qs;
    qv.z = (q_w[6]*xn0 + q_w[7]*xn1 + q_w[8]*xn2)*qs;
    qv.w = 0.0f;
    ((float4*)ws_q)[pix] = qv;
}

// grid: (NPIX/(256*QPT), NC) = (9, 32); each thread: QPT queries vs KPC keys
__global__ __launch_bounds__(256) void k2_attn(const float* __restrict__ ws)
{
    const float* ws_q  = ws + OFF_Q;
    const float* ws_kv = ws + OFF_KV;
    float* ws_part     = (float*)(ws + OFF_PART);

    __shared__ float4 lkv[KPC*6/4];   // 384 float4 = 6KB
    int tid   = threadIdx.x;
    int chunk = blockIdx.y;
    const float4* src = (const float4*)(ws_kv + chunk*KPC*6);
    #pragma unroll
    for (int i=tid; i<KPC*6/4; i+=256) lkv[i]=src[i];
    __syncthreads();

    int qbase = blockIdx.x*(256*QPT) + tid;   // strided by 256 across QPT
    float qx[QPT], qy[QPT], qz[QPT];
    #pragma unroll
    for (int j=0;j<QPT;j++){
        float4 q = ((const float4*)ws_q)[qbase + j*256];
        qx[j]=q.x; qy[j]=q.y; qz[j]=q.z;
    }

    float s[QPT], a0[QPT], a1[QPT], a2[QPT];
    #pragma unroll
    for (int j=0;j<QPT;j++){ s[j]=0.f; a0[j]=0.f; a1[j]=0.f; a2[j]=0.f; }

    for (int kk=0; kk<KPC/2; ++kk){
        float4 A = lkv[kk*3+0];
        float4 B = lkv[kk*3+1];
        float4 C = lkv[kk*3+2];
        // key pair layout: k0(A.x,A.y,A.z) v0(A.w,B.x,B.y) | k1(B.z,B.w,C.x) v1(C.y,C.z,C.w)
        #pragma unroll
        for (int j=0;j<QPT;j++){
            float l0 = qx[j]*A.x + qy[j]*A.y + qz[j]*A.z;
            float p0 = exp2f(l0);
            s[j] += p0; a0[j] += p0*A.w; a1[j] += p0*B.x; a2[j] += p0*B.y;
            float l1 = qx[j]*B.z + qy[j]*B.w + qz[j]*C.x;
            float p1 = exp2f(l1);
            s[j] += p1; a0[j] += p1*C.y; a1[j] += p1*C.z; a2[j] += p1*C.w;
        }
    }
    float4* dst = (float4*)ws_part + chunk*NPIX + qbase;
    #pragma unroll
    for (int j=0;j<QPT;j++) dst[j*256] = make_float4(s[j],a0[j],a1[j],a2[j]);
}

__global__ __launch_bounds__(256) void k3_final(
    const float* __restrict__ ws,
    const float* __restrict__ mo_w1, const float* __restrict__ mo_b1,
    const float* __restrict__ mo_w2, const float* __restrict__ mo_b2,
    const float* __restrict__ n2_g,  const float* __restrict__ n2_b,
    const float* __restrict__ fuse_w,const float* __restrict__ fuse_b,
    float* __restrict__ out)
{
    const float* ws_eehs = ws + OFF_EEHS;
    const float* ws_mm   = ws + OFF_MM;
    const float* ws_part = ws + OFF_PART;

    int tid = threadIdx.x;
    int pix = blockIdx.x*256 + tid;

    float s=0.0f, a0=0.0f, a1=0.0f, a2=0.0f;
    #pragma unroll
    for (int c=0;c<NC;c++){
        float4 p = ((const float4*)ws_part)[c*NPIX + pix];
        s+=p.x; a0+=p.y; a1+=p.z; a2+=p.w;
    }
    float invs = 1.0f/s;
    float xa0 = a0*invs, xa1 = a1*invs, xa2 = a2*invs;

    // mlp_out
    float h6[6];
    #pragma unroll
    for (int i=0;i<6;i++){
        float a = mo_w1[i*3+0]*xa0 + mo_w1[i*3+1]*xa1 + mo_w1[i*3+2]*xa2 + mo_b1[i];
        h6[i] = gelu_tanh(a);
    }
    float y[3];
    #pragma unroll
    for (int i=0;i<3;i++){
        float a = mo_b2[i];
        #pragma unroll
        for (int k=0;k<6;k++) a += mo_w2[i*6+k]*h6[k];
        y[i]=a;
    }
    float m  = (y[0]+y[1]+y[2])*(1.0f/3.0f);
    float d0 = y[0]-m, d1 = y[1]-m, d2 = y[2]-m;
    float var = (d0*d0+d1*d1+d2*d2)*(1.0f/3.0f);
    float inv = 1.0f/sqrtf(var+1e-5f);
    float t0 = d0*inv*n2_g[0]+n2_b[0];
    float t1 = d1*inv*n2_g[1]+n2_b[1];
    float t2 = d2*inv*n2_g[2]+n2_b[2];

    // PSF: S_n normalize + blend
    float4 e  = ((const float4*)ws_eehs)[pix*2+0];   // EE, S
    float4 hh = ((const float4*)ws_eehs)[pix*2+1];   // HH
    int b = (pix >= HW) ? 1 : 0;
    int base = b*144;
    float mn = INFINITY, mx = -INFINITY;
    for (int i=0;i<144;i++){
        mn = fminf(mn, ws_mm[(base+i)*2+0]);
        mx = fmaxf(mx, ws_mm[(base+i)*2+1]);
    }
    float Sn = (e.w - mn)/(mx - mn);
    float f0 = Sn*e.x + (1.0f-Sn)*hh.x;
    float f1 = Sn*e.y + (1.0f-Sn)*hh.y;
    float f2 = Sn*e.z + (1.0f-Sn)*hh.z;

    int pos = pix - b*HW;
    #pragma unroll
    for (int o=0;o<3;o++){
        float val = fuse_b[o]
                  + fuse_w[o*6+0]*t0 + fuse_w[o*6+1]*t1 + fuse_w[o*6+2]*t2
                  + fuse_w[o*6+3]*f0 + fuse_w[o*6+4]*f1 + fuse_w[o*6+5]*f2;
        out[(b*3+o)*HW + pos] = val;
    }
}

extern "C" void kernel_launch(void* const* d_in, const int* in_sizes, int n_in,
                              void* d_out, int out_size, void* d_ws, size_t ws_size,
                              hipStream_t stream) {
    const float* front  = (const float*)d_in[0];
    const float* back   = (const float*)d_in[1];
    // d_in[2] = mask (unused by reference)
    const float* bg     = (const float*)d_in[3];
    const float* mi_w1  = (const float*)d_in[4];
    const float* mi_b1  = (const float*)d_in[5];
    const float* mi_w2  = (const float*)d_in[6];
    const float* mi_b2  = (const float*)d_in[7];
    const float* q_w    = (const float*)d_in[8];
    const float* k_w    = (const float*)d_in[9];
    const float* v_w    = (const float*)d_in[10];
    const float* mo_w1  = (const float*)d_in[11];
    const float* mo_b1  = (const float*)d_in[12];
    const float* mo_w2  = (const float*)d_in[13];
    const float* mo_b2  = (const float*)d_in[14];
    const float* n1_g   = (const float*)d_in[15];
    const float* n1_b   = (const float*)d_in[16];
    const float* n2_g   = (const float*)d_in[17];
    const float* n2_b   = (const float*)d_in[18];
    const float* e_w    = (const float*)d_in[19];
    const float* e_b    = (const float*)d_in[20];
    const float* f_w    = (const float*)d_in[21];
    const float* f_b    = (const float*)d_in[22];
    const float* g_w    = (const float*)d_in[23];
    const float* g_b    = (const float*)d_in[24];
    const float* h_w    = (const float*)d_in[25];
    const float* h_b    = (const float*)d_in[26];
    const float* fuse_w = (const float*)d_in[27];
    const float* fuse_b = (const float*)d_in[28];

    float* ws  = (float*)d_ws;
    float* out = (float*)d_out;

    k1_prep<<<dim3(NPIX/64), 64, 0, stream>>>(
        front, back, bg, mi_w1, mi_b1, mi_w2, mi_b2, q_w, k_w, v_w,
        n1_g, n1_b, e_w, e_b, f_w, f_b, g_w, g_b, h_w, h_b, ws);

    k2_attn<<<dim3(NPIX/(256*QPT), NC), 256, 0, stream>>>(ws);

    k3_final<<<dim3(NPIX/256), 256, 0, stream>>>(
        ws, mo_w1, mo_b1, mo_w2, mo_b2, n2_g, n2_b, fuse_w, fuse_b, out);
}

// Round 3
// 107.667 us; speedup vs baseline: 1.1967x; 1.1967x over previous
//
#include <hip/hip_runtime.h>
#include <math.h>

#define HW    9216      // 96*96
#define NPIX  18432     // B*HW
#define NKEY  8192

// ws layout (float units)
#define OFF_Q    0                      // [NPIX][4]
#define OFF_KV   (OFF_Q + NPIX*4)       // [NKEY][6]
#define OFF_EEHS (OFF_KV + NKEY*6)      // [NPIX][8]  : EE0..2,S | HH0..2,pad
#define OFF_MM   (OFF_EEHS + NPIX*8)    // [288][2]   : per-block S min,max (k1 grid = 288)
#define OFF_PART (OFF_MM + 576)         // [NC][NPIX][4] : s, sv0, sv1, sv2

__device__ __forceinline__ float gelu_tanh(float x){
    float u = 0.7978845608028654f*(x + 0.044715f*x*x*x);
    return 0.5f*x*(1.0f + tanhf(u));
}

__global__ __launch_bounds__(64) void k1_prep(
    const float* __restrict__ front, const float* __restrict__ back,
    const float* __restrict__ bg,
    const float* __restrict__ mi_w1, const float* __restrict__ mi_b1,
    const float* __restrict__ mi_w2, const float* __restrict__ mi_b2,
    const float* __restrict__ q_w,  const float* __restrict__ k_w,
    const float* __restrict__ v_w,
    const float* __restrict__ n1_g, const float* __restrict__ n1_b,
    const float* __restrict__ e_w,  const float* __restrict__ e_b,
    const float* __restrict__ f_w,  const float* __restrict__ f_b,
    const float* __restrict__ g_w,  const float* __restrict__ g_b,
    const float* __restrict__ h_w,  const float* __restrict__ h_b,
    float* __restrict__ ws)
{
    float* ws_q    = ws + OFF_Q;
    float* ws_kv   = ws + OFF_KV;
    float* ws_eehs = ws + OFF_EEHS;
    float* ws_mm   = ws + OFF_MM;

    int tid = threadIdx.x;
    int pix = blockIdx.x*64 + tid;      // 0..18431

    // ---------- keys: k,v from codebook ----------
    if (pix < NKEY){
        float c0 = bg[pix], c1 = bg[NKEY+pix], c2 = bg[2*NKEY+pix];
        #pragma unroll
        for (int i=0;i<3;i++){
            ws_kv[pix*6+i]   = k_w[i*3+0]*c0 + k_w[i*3+1]*c1 + k_w[i*3+2]*c2;
            ws_kv[pix*6+3+i] = v_w[i*3+0]*c0 + v_w[i*3+1]*c1 + v_w[i*3+2]*c2;
        }
    }

    int b   = (pix >= HW) ? 1 : 0;
    int pos = pix - b*HW;
    int y   = pos / 96;
    int x   = pos - y*96;
    const float* fbase = front + b*3*HW;
    const float* bbase = back  + b*3*HW;

    // ---------- 7x7 zero-padded box sums ----------
    float s1f[3]={0,0,0}, s2f[3]={0,0,0}, s1b[3]={0,0,0}, s2b[3]={0,0,0};
    for (int dy=-3; dy<=3; ++dy){
        int yy = y+dy;
        if (yy < 0 || yy >= 96) continue;
        for (int dx=-3; dx<=3; ++dx){
            int xx = x+dx;
            if (xx < 0 || xx >= 96) continue;
            int off = yy*96+xx;
            #pragma unroll
            for (int c=0;c<3;c++){
                float fv = fbase[c*HW+off];
                float bv = bbase[c*HW+off];
                s1f[c]+=fv; s2f[c]+=fv*fv;
                s1b[c]+=bv; s2b[c]+=bv*bv;
            }
        }
    }

    float xnf[3], adain[3], bn[3], bval[3];
    #pragma unroll
    for (int c=0;c<3;c++){
        float mf = s1f[c]*(1.0f/49.0f);
        float vf = (s2f[c] - s1f[c]*s1f[c]*(1.0f/49.0f))*(1.0f/48.0f);
        float fv = fbase[c*HW+pos];
        xnf[c] = (fv - mf)/(sqrtf(vf)+1e-8f);

        float mb = s1b[c]*(1.0f/49.0f);
        float vb = (s2b[c] - s1b[c]*s1b[c]*(1.0f/49.0f))*(1.0f/48.0f);
        float bb = bbase[c*HW+pos];
        bval[c]  = bb;
        float stdb = sqrtf(vb);
        adain[c] = xnf[c]*stdb + mb;         // no eps on y_std
        bn[c]    = (bb - mb)/(stdb + 1e-8f);
    }

    float EE[3], FF[3], GG[3], HHv[3];
    #pragma unroll
    for (int i=0;i<3;i++){
        EE[i]  = e_w[i*3+0]*adain[0] + e_w[i*3+1]*adain[1] + e_w[i*3+2]*adain[2] + e_b[i];
        FF[i]  = f_w[i*3+0]*xnf[0]   + f_w[i*3+1]*xnf[1]   + f_w[i*3+2]*xnf[2]   + f_b[i];
        GG[i]  = g_w[i*3+0]*bn[0]    + g_w[i*3+1]*bn[1]    + g_w[i*3+2]*bn[2]    + g_b[i];
        HHv[i] = h_w[i*3+0]*bval[0]  + h_w[i*3+1]*bval[1]  + h_w[i*3+2]*bval[2]  + h_b[i];
    }
    float num = FF[0]*GG[0]+FF[1]*GG[1]+FF[2]*GG[2];
    float fn  = sqrtf(FF[0]*FF[0]+FF[1]*FF[1]+FF[2]*FF[2]);
    float gn  = sqrtf(GG[0]*GG[0]+GG[1]*GG[1]+GG[2]*GG[2]);
    float S   = num/(fn*gn);

    float4* eehs4 = (float4*)ws_eehs;
    eehs4[pix*2+0] = make_float4(EE[0],EE[1],EE[2],S);
    eehs4[pix*2+1] = make_float4(HHv[0],HHv[1],HHv[2],0.0f);

    // ---------- per-block S min/max via wave shuffle (block == 1 wave) ----------
    float mn = S, mx = S;
    #pragma unroll
    for (int off=32; off>0; off>>=1){
        mn = fminf(mn, __shfl_xor(mn, off));
        mx = fmaxf(mx, __shfl_xor(mx, off));
    }
    if (tid==0){ ws_mm[blockIdx.x*2+0]=mn; ws_mm[blockIdx.x*2+1]=mx; }

    // ---------- token q : mlp_in -> ln -> q_w, pre-scaled by scale*log2e ----------
    float xt0 = fbase[0*HW+pos], xt1 = fbase[1*HW+pos], xt2 = fbase[2*HW+pos];
    float h6[6];
    #pragma unroll
    for (int i=0;i<6;i++){
        float a = mi_w1[i*3+0]*xt0 + mi_w1[i*3+1]*xt1 + mi_w1[i*3+2]*xt2 + mi_b1[i];
        h6[i] = gelu_tanh(a);
    }
    float x2[3];
    #pragma unroll
    for (int i=0;i<3;i++){
        float a = mi_b2[i];
        #pragma unroll
        for (int k=0;k<6;k++) a += mi_w2[i*6+k]*h6[k];
        x2[i]=a;
    }
    float m  = (x2[0]+x2[1]+x2[2])*(1.0f/3.0f);
    float d0 = x2[0]-m, d1 = x2[1]-m, d2 = x2[2]-m;
    float var = (d0*d0+d1*d1+d2*d2)*(1.0f/3.0f);
    float inv = 1.0f/sqrtf(var+1e-5f);
    float xn0 = d0*inv*n1_g[0]+n1_b[0];
    float xn1 = d1*inv*n1_g[1]+n1_b[1];
    float xn2 = d2*inv*n1_g[2]+n1_b[2];
    const float qs = 0.5773502691896258f * 1.4426950408889634f; // d^-0.5 * log2(e)
    float4 qv;
    qv.x = (q_w[0]*xn0 + q_w[1]*xn1 + q_w[2]*xn2)*qs;
    qv.y = (q_w[3]*xn0 + q_w[4]*xn1 + q_w[5]*xn2)*qs;
    qv.z = (q_w[6]*xn0 + q_w[7]*xn1 + q_w[8]*xn2)*qs;
    qv.w = 0.0f;
    ((float4*)ws_q)[pix] = qv;
}

// grid: (NPIX/(256*QPT_T), NKEY/KPC_T); each thread: QPT_T queries vs KPC_T keys
template<int QPT_T, int KPC_T>
__global__ __launch_bounds__(256, 2) void k2_attn(const float* __restrict__ ws)
{
    const float* ws_q  = ws + OFF_Q;
    const float* ws_kv = ws + OFF_KV;
    float* ws_part     = (float*)(ws + OFF_PART);

    __shared__ float4 lkv[KPC_T*6/4];
    int tid   = threadIdx.x;
    int chunk = blockIdx.y;
    const float4* src = (const float4*)(ws_kv + chunk*KPC_T*6);
    for (int i=tid; i<KPC_T*6/4; i+=256) lkv[i]=src[i];
    __syncthreads();

    int qbase = blockIdx.x*(256*QPT_T) + tid;   // strided by 256 across QPT_T
    float qx[QPT_T], qy[QPT_T], qz[QPT_T];
    #pragma unroll
    for (int j=0;j<QPT_T;j++){
        float4 q = ((const float4*)ws_q)[qbase + j*256];
        qx[j]=q.x; qy[j]=q.y; qz[j]=q.z;
    }

    float s[QPT_T], a0[QPT_T], a1[QPT_T], a2[QPT_T];
    #pragma unroll
    for (int j=0;j<QPT_T;j++){ s[j]=0.f; a0[j]=0.f; a1[j]=0.f; a2[j]=0.f; }

    for (int kk=0; kk<KPC_T/2; ++kk){
        float4 A = lkv[kk*3+0];
        float4 B = lkv[kk*3+1];
        float4 C = lkv[kk*3+2];
        // key pair layout: k0(A.x,A.y,A.z) v0(A.w,B.x,B.y) | k1(B.z,B.w,C.x) v1(C.y,C.z,C.w)
        #pragma unroll
        for (int j=0;j<QPT_T;j++){
            float l0 = qx[j]*A.x + qy[j]*A.y + qz[j]*A.z;
            float p0 = exp2f(l0);
            s[j] += p0; a0[j] += p0*A.w; a1[j] += p0*B.x; a2[j] += p0*B.y;
        }
        #pragma unroll
        for (int j=0;j<QPT_T;j++){
            float l1 = qx[j]*B.z + qy[j]*B.w + qz[j]*C.x;
            float p1 = exp2f(l1);
            s[j] += p1; a0[j] += p1*C.y; a1[j] += p1*C.z; a2[j] += p1*C.w;
        }
    }
    float4* dst = (float4*)ws_part + (size_t)chunk*NPIX + qbase;
    #pragma unroll
    for (int j=0;j<QPT_T;j++) dst[j*256] = make_float4(s[j],a0[j],a1[j],a2[j]);
}

// block = 64 (one wave), grid = NPIX/64 = 288
template<int NC_T>
__global__ __launch_bounds__(64) void k3_final(
    const float* __restrict__ ws,
    const float* __restrict__ mo_w1, const float* __restrict__ mo_b1,
    const float* __restrict__ mo_w2, const float* __restrict__ mo_b2,
    const float* __restrict__ n2_g,  const float* __restrict__ n2_b,
    const float* __restrict__ fuse_w,const float* __restrict__ fuse_b,
    float* __restrict__ out)
{
    const float* ws_eehs = ws + OFF_EEHS;
    const float* ws_mm   = ws + OFF_MM;
    const float* ws_part = ws + OFF_PART;

    int tid = threadIdx.x;
    int pix = blockIdx.x*64 + tid;
    int b   = (pix >= HW) ? 1 : 0;     // uniform per block (9216 % 64 == 0)

    // ---------- batch S min/max: wave-cooperative over 144 k1-block entries ----------
    int base = b*144;
    float mn = INFINITY, mx = -INFINITY;
    for (int i=tid; i<144; i+=64){
        mn = fminf(mn, ws_mm[(base+i)*2+0]);
        mx = fmaxf(mx, ws_mm[(base+i)*2+1]);
    }
    #pragma unroll
    for (int off=32; off>0; off>>=1){
        mn = fminf(mn, __shfl_xor(mn, off));
        mx = fmaxf(mx, __shfl_xor(mx, off));
    }

    // ---------- merge attention partials ----------
    float s=0.0f, a0=0.0f, a1=0.0f, a2=0.0f;
    #pragma unroll
    for (int c=0;c<NC_T;c++){
        float4 p = ((const float4*)ws_part)[(size_t)c*NPIX + pix];
        s+=p.x; a0+=p.y; a1+=p.z; a2+=p.w;
    }
    float invs = 1.0f/s;
    float xa0 = a0*invs, xa1 = a1*invs, xa2 = a2*invs;

    // mlp_out
    float h6[6];
    #pragma unroll
    for (int i=0;i<6;i++){
        float a = mo_w1[i*3+0]*xa0 + mo_w1[i*3+1]*xa1 + mo_w1[i*3+2]*xa2 + mo_b1[i];
        h6[i] = gelu_tanh(a);
    }
    float y[3];
    #pragma unroll
    for (int i=0;i<3;i++){
        float a = mo_b2[i];
        #pragma unroll
        for (int k=0;k<6;k++) a += mo_w2[i*6+k]*h6[k];
        y[i]=a;
    }
    float m  = (y[0]+y[1]+y[2])*(1.0f/3.0f);
    float d0 = y[0]-m, d1 = y[1]-m, d2 = y[2]-m;
    float var = (d0*d0+d1*d1+d2*d2)*(1.0f/3.0f);
    float inv = 1.0f/sqrtf(var+1e-5f);
    float t0 = d0*inv*n2_g[0]+n2_b[0];
    float t1 = d1*inv*n2_g[1]+n2_b[1];
    float t2 = d2*inv*n2_g[2]+n2_b[2];

    // PSF: S_n normalize + blend
    float4 e  = ((const float4*)ws_eehs)[pix*2+0];   // EE, S
    float4 hh = ((const float4*)ws_eehs)[pix*2+1];   // HH
    float Sn = (e.w - mn)/(mx - mn);
    float f0 = Sn*e.x + (1.0f-Sn)*hh.x;
    float f1 = Sn*e.y + (1.0f-Sn)*hh.y;
    float f2 = Sn*e.z + (1.0f-Sn)*hh.z;

    int pos = pix - b*HW;
    #pragma unroll
    for (int o=0;o<3;o++){
        float val = fuse_b[o]
                  + fuse_w[o*6+0]*t0 + fuse_w[o*6+1]*t1 + fuse_w[o*6+2]*t2
                  + fuse_w[o*6+3]*f0 + fuse_w[o*6+4]*f1 + fuse_w[o*6+5]*f2;
        out[(b*3+o)*HW + pos] = val;
    }
}

extern "C" void kernel_launch(void* const* d_in, const int* in_sizes, int n_in,
                              void* d_out, int out_size, void* d_ws, size_t ws_size,
                              hipStream_t stream) {
    const float* front  = (const float*)d_in[0];
    const float* back   = (const float*)d_in[1];
    // d_in[2] = mask (unused by reference)
    const float* bg     = (const float*)d_in[3];
    const float* mi_w1  = (const float*)d_in[4];
    const float* mi_b1  = (const float*)d_in[5];
    const float* mi_w2  = (const float*)d_in[6];
    const float* mi_b2  = (const float*)d_in[7];
    const float* q_w    = (const float*)d_in[8];
    const float* k_w    = (const float*)d_in[9];
    const float* v_w    = (const float*)d_in[10];
    const float* mo_w1  = (const float*)d_in[11];
    const float* mo_b1  = (const float*)d_in[12];
    const float* mo_w2  = (const float*)d_in[13];
    const float* mo_b2  = (const float*)d_in[14];
    const float* n1_g   = (const float*)d_in[15];
    const float* n1_b   = (const float*)d_in[16];
    const float* n2_g   = (const float*)d_in[17];
    const float* n2_b   = (const float*)d_in[18];
    const float* e_w    = (const float*)d_in[19];
    const float* e_b    = (const float*)d_in[20];
    const float* f_w    = (const float*)d_in[21];
    const float* f_b    = (const float*)d_in[22];
    const float* g_w    = (const float*)d_in[23];
    const float* g_b    = (const float*)d_in[24];
    const float* h_w    = (const float*)d_in[25];
    const float* h_b    = (const float*)d_in[26];
    const float* fuse_w = (const float*)d_in[27];
    const float* fuse_b = (const float*)d_in[28];

    float* ws  = (float*)d_ws;
    float* out = (float*)d_out;

    k1_prep<<<dim3(NPIX/64), 64, 0, stream>>>(
        front, back, bg, mi_w1, mi_b1, mi_w2, mi_b2, q_w, k_w, v_w,
        n1_g, n1_b, e_w, e_b, f_w, f_b, g_w, g_b, h_w, h_b, ws);

    size_t need64 = (size_t)(OFF_PART + 64*NPIX*4) * sizeof(float);
    if (ws_size >= need64){
        // primary: QPT=8, NC=64 (KPC=128): 576 blocks, 9 waves/CU, ~19 MB ws
        k2_attn<8,128><<<dim3(NPIX/(256*8), 64), 256, 0, stream>>>(ws);
        k3_final<64><<<dim3(NPIX/64), 64, 0, stream>>>(
            ws, mo_w1, mo_b1, mo_w2, mo_b2, n2_g, n2_b, fuse_w, fuse_b, out);
    } else {
        // fallback: QPT=4, NC=32 (KPC=256): 576 blocks, ~10.5 MB ws
        k2_attn<4,256><<<dim3(NPIX/(256*4), 32), 256, 0, stream>>>(ws);
        k3_final<32><<<dim3(NPIX/64), 64, 0, stream>>>(
            ws, mo_w1, mo_b1, mo_w2, mo_b2, n2_g, n2_b, fuse_w, fuse_b, out);
    }
}

// Round 4
// 78.741 us; speedup vs baseline: 1.6363x; 1.3674x over previous
//
#include <hip/hip_runtime.h>
#include <math.h>

#define HW    9216      // 96*96
#define NPIX  18432     // B*HW
#define NKEY  8192

// ws layout (float units)
#define OFF_Q    0                      // [NPIX][4]
#define OFF_KV   (OFF_Q + NPIX*4)       // [NKEY][6]
#define OFF_EEHS (OFF_KV + NKEY*6)      // [NPIX][8]  : EE0..2,S | HH0..2,pad
#define OFF_MM   (OFF_EEHS + NPIX*8)    // [288][2]   : per-block S min,max (k1 grid = 288)
#define OFF_PART (OFF_MM + 576)         // [NC][NPIX][4] : s, sv0, sv1, sv2

#if __has_builtin(__builtin_amdgcn_exp2f)
#define EXP2(x) __builtin_amdgcn_exp2f(x)
#else
#define EXP2(x) exp2f(x)
#endif

__device__ __forceinline__ float gelu_tanh(float x){
    float u = 0.7978845608028654f*(x + 0.044715f*x*x*x);
    return 0.5f*x*(1.0f + tanhf(u));
}

__global__ __launch_bounds__(64) void k1_prep(
    const float* __restrict__ front, const float* __restrict__ back,
    const float* __restrict__ bg,
    const float* __restrict__ mi_w1, const float* __restrict__ mi_b1,
    const float* __restrict__ mi_w2, const float* __restrict__ mi_b2,
    const float* __restrict__ q_w,  const float* __restrict__ k_w,
    const float* __restrict__ v_w,
    const float* __restrict__ n1_g, const float* __restrict__ n1_b,
    const float* __restrict__ e_w,  const float* __restrict__ e_b,
    const float* __restrict__ f_w,  const float* __restrict__ f_b,
    const float* __restrict__ g_w,  const float* __restrict__ g_b,
    const float* __restrict__ h_w,  const float* __restrict__ h_b,
    float* __restrict__ ws)
{
    float* ws_q    = ws + OFF_Q;
    float* ws_kv   = ws + OFF_KV;
    float* ws_eehs = ws + OFF_EEHS;
    float* ws_mm   = ws + OFF_MM;

    int tid = threadIdx.x;
    int pix = blockIdx.x*64 + tid;      // 0..18431

    // ---------- keys: k,v from codebook ----------
    if (pix < NKEY){
        float c0 = bg[pix], c1 = bg[NKEY+pix], c2 = bg[2*NKEY+pix];
        #pragma unroll
        for (int i=0;i<3;i++){
            ws_kv[pix*6+i]   = k_w[i*3+0]*c0 + k_w[i*3+1]*c1 + k_w[i*3+2]*c2;
            ws_kv[pix*6+3+i] = v_w[i*3+0]*c0 + v_w[i*3+1]*c1 + v_w[i*3+2]*c2;
        }
    }

    int b   = (pix >= HW) ? 1 : 0;
    int pos = pix - b*HW;
    int y   = pos / 96;
    int x   = pos - y*96;
    const float* fbase = front + b*3*HW;
    const float* bbase = back  + b*3*HW;

    // ---------- 7x7 zero-padded box sums ----------
    float s1f[3]={0,0,0}, s2f[3]={0,0,0}, s1b[3]={0,0,0}, s2b[3]={0,0,0};
    for (int dy=-3; dy<=3; ++dy){
        int yy = y+dy;
        if (yy < 0 || yy >= 96) continue;
        for (int dx=-3; dx<=3; ++dx){
            int xx = x+dx;
            if (xx < 0 || xx >= 96) continue;
            int off = yy*96+xx;
            #pragma unroll
            for (int c=0;c<3;c++){
                float fv = fbase[c*HW+off];
                float bv = bbase[c*HW+off];
                s1f[c]+=fv; s2f[c]+=fv*fv;
                s1b[c]+=bv; s2b[c]+=bv*bv;
            }
        }
    }

    float xnf[3], adain[3], bn[3], bval[3];
    #pragma unroll
    for (int c=0;c<3;c++){
        float mf = s1f[c]*(1.0f/49.0f);
        float vf = (s2f[c] - s1f[c]*s1f[c]*(1.0f/49.0f))*(1.0f/48.0f);
        float fv = fbase[c*HW+pos];
        xnf[c] = (fv - mf)/(sqrtf(vf)+1e-8f);

        float mb = s1b[c]*(1.0f/49.0f);
        float vb = (s2b[c] - s1b[c]*s1b[c]*(1.0f/49.0f))*(1.0f/48.0f);
        float bb = bbase[c*HW+pos];
        bval[c]  = bb;
        float stdb = sqrtf(vb);
        adain[c] = xnf[c]*stdb + mb;         // no eps on y_std
        bn[c]    = (bb - mb)/(stdb + 1e-8f);
    }

    float EE[3], FF[3], GG[3], HHv[3];
    #pragma unroll
    for (int i=0;i<3;i++){
        EE[i]  = e_w[i*3+0]*adain[0] + e_w[i*3+1]*adain[1] + e_w[i*3+2]*adain[2] + e_b[i];
        FF[i]  = f_w[i*3+0]*xnf[0]   + f_w[i*3+1]*xnf[1]   + f_w[i*3+2]*xnf[2]   + f_b[i];
        GG[i]  = g_w[i*3+0]*bn[0]    + g_w[i*3+1]*bn[1]    + g_w[i*3+2]*bn[2]    + g_b[i];
        HHv[i] = h_w[i*3+0]*bval[0]  + h_w[i*3+1]*bval[1]  + h_w[i*3+2]*bval[2]  + h_b[i];
    }
    float num = FF[0]*GG[0]+FF[1]*GG[1]+FF[2]*GG[2];
    float fn  = sqrtf(FF[0]*FF[0]+FF[1]*FF[1]+FF[2]*FF[2]);
    float gn  = sqrtf(GG[0]*GG[0]+GG[1]*GG[1]+GG[2]*GG[2]);
    float S   = num/(fn*gn);

    float4* eehs4 = (float4*)ws_eehs;
    eehs4[pix*2+0] = make_float4(EE[0],EE[1],EE[2],S);
    eehs4[pix*2+1] = make_float4(HHv[0],HHv[1],HHv[2],0.0f);

    // ---------- per-block S min/max via wave shuffle (block == 1 wave) ----------
    float mn = S, mx = S;
    #pragma unroll
    for (int off=32; off>0; off>>=1){
        mn = fminf(mn, __shfl_xor(mn, off));
        mx = fmaxf(mx, __shfl_xor(mx, off));
    }
    if (tid==0){ ws_mm[blockIdx.x*2+0]=mn; ws_mm[blockIdx.x*2+1]=mx; }

    // ---------- token q : mlp_in -> ln -> q_w, pre-scaled by scale*log2e ----------
    float xt0 = fbase[0*HW+pos], xt1 = fbase[1*HW+pos], xt2 = fbase[2*HW+pos];
    float h6[6];
    #pragma unroll
    for (int i=0;i<6;i++){
        float a = mi_w1[i*3+0]*xt0 + mi_w1[i*3+1]*xt1 + mi_w1[i*3+2]*xt2 + mi_b1[i];
        h6[i] = gelu_tanh(a);
    }
    float x2[3];
    #pragma unroll
    for (int i=0;i<3;i++){
        float a = mi_b2[i];
        #pragma unroll
        for (int k=0;k<6;k++) a += mi_w2[i*6+k]*h6[k];
        x2[i]=a;
    }
    float m  = (x2[0]+x2[1]+x2[2])*(1.0f/3.0f);
    float d0 = x2[0]-m, d1 = x2[1]-m, d2 = x2[2]-m;
    float var = (d0*d0+d1*d1+d2*d2)*(1.0f/3.0f);
    float inv = 1.0f/sqrtf(var+1e-5f);
    float xn0 = d0*inv*n1_g[0]+n1_b[0];
    float xn1 = d1*inv*n1_g[1]+n1_b[1];
    float xn2 = d2*inv*n1_g[2]+n1_b[2];
    const float qs = 0.5773502691896258f * 1.4426950408889634f; // d^-0.5 * log2(e)
    float4 qv;
    qv.x = (q_w[0]*xn0 + q_w[1]*xn1 + q_w[2]*xn2)*qs;
    qv.y = (q_w[3]*xn0 + q_w[4]*xn1 + q_w[5]*xn2)*qs;
    qv.z = (q_w[6]*xn0 + q_w[7]*xn1 + q_w[8]*xn2)*qs;
    qv.w = 0.0f;
    ((float4*)ws_q)[pix] = qv;
}

// ---------------- k2: 8 queries per thread, ALL state in named scalars ----------------
// grid: (NPIX/(256*8), NKEY/KPC_T); LDS holds KPC_T keys (k0,k1,k2,v0,v1,v2 packed)

#define DECLQ(J) float qx##J, qy##J, qz##J; \
                 float s##J=0.f, a0##J=0.f, a1##J=0.f, a2##J=0.f;

#define LOADQ(J) { float4 qq = q4[qbase + J*256]; qx##J=qq.x; qy##J=qq.y; qz##J=qq.z; }

#define QSTEP(J) { \
    float l0 = fmaf(qz##J, A.z, fmaf(qy##J, A.y, qx##J*A.x)); \
    float p0 = EXP2(l0); \
    s##J += p0; \
    a0##J = fmaf(p0, A.w, a0##J); \
    a1##J = fmaf(p0, B.x, a1##J); \
    a2##J = fmaf(p0, B.y, a2##J); \
    float l1 = fmaf(qz##J, C.x, fmaf(qy##J, B.w, qx##J*B.z)); \
    float p1 = EXP2(l1); \
    s##J += p1; \
    a0##J = fmaf(p1, C.y, a0##J); \
    a1##J = fmaf(p1, C.z, a1##J); \
    a2##J = fmaf(p1, C.w, a2##J); }

#define STOREP(J) dst[J*256] = make_float4(s##J, a0##J, a1##J, a2##J);

template<int KPC_T>
__global__ __launch_bounds__(256) void k2_attn(const float* __restrict__ ws)
{
    const float* ws_q  = ws + OFF_Q;
    const float* ws_kv = ws + OFF_KV;
    float* ws_part     = (float*)(ws + OFF_PART);

    __shared__ float4 lkv[KPC_T*6/4];
    int tid   = threadIdx.x;
    int chunk = blockIdx.y;
    const float4* src = (const float4*)(ws_kv + chunk*KPC_T*6);
    for (int i=tid; i<KPC_T*6/4; i+=256) lkv[i]=src[i];
    __syncthreads();

    const float4* q4 = (const float4*)ws_q;
    int qbase = blockIdx.x*(256*8) + tid;   // strided by 256 across 8 queries

    DECLQ(0) DECLQ(1) DECLQ(2) DECLQ(3)
    DECLQ(4) DECLQ(5) DECLQ(6) DECLQ(7)
    LOADQ(0) LOADQ(1) LOADQ(2) LOADQ(3)
    LOADQ(4) LOADQ(5) LOADQ(6) LOADQ(7)

    for (int kk=0; kk<KPC_T/2; ++kk){
        float4 A = lkv[kk*3+0];
        float4 B = lkv[kk*3+1];
        float4 C = lkv[kk*3+2];
        // key pair layout: k0(A.x,A.y,A.z) v0(A.w,B.x,B.y) | k1(B.z,B.w,C.x) v1(C.y,C.z,C.w)
        QSTEP(0) QSTEP(1) QSTEP(2) QSTEP(3)
        QSTEP(4) QSTEP(5) QSTEP(6) QSTEP(7)
    }

    float4* dst = (float4*)ws_part + (size_t)chunk*NPIX + qbase;
    STOREP(0) STOREP(1) STOREP(2) STOREP(3)
    STOREP(4) STOREP(5) STOREP(6) STOREP(7)
}

// block = 64 (one wave), grid = NPIX/64 = 288
template<int NC_T>
__global__ __launch_bounds__(64) void k3_final(
    const float* __restrict__ ws,
    const float* __restrict__ mo_w1, const float* __restrict__ mo_b1,
    const float* __restrict__ mo_w2, const float* __restrict__ mo_b2,
    const float* __restrict__ n2_g,  const float* __restrict__ n2_b,
    const float* __restrict__ fuse_w,const float* __restrict__ fuse_b,
    float* __restrict__ out)
{
    const float* ws_eehs = ws + OFF_EEHS;
    const float* ws_mm   = ws + OFF_MM;
    const float* ws_part = ws + OFF_PART;

    int tid = threadIdx.x;
    int pix = blockIdx.x*64 + tid;
    int b   = (pix >= HW) ? 1 : 0;     // uniform per block (9216 % 64 == 0)

    // ---------- batch S min/max: wave-cooperative over 144 k1-block entries ----------
    int base = b*144;
    float mn = INFINITY, mx = -INFINITY;
    for (int i=tid; i<144; i+=64){
        mn = fminf(mn, ws_mm[(base+i)*2+0]);
        mx = fmaxf(mx, ws_mm[(base+i)*2+1]);
    }
    #pragma unroll
    for (int off=32; off>0; off>>=1){
        mn = fminf(mn, __shfl_xor(mn, off));
        mx = fmaxf(mx, __shfl_xor(mx, off));
    }

    // ---------- merge attention partials ----------
    float s=0.0f, a0=0.0f, a1=0.0f, a2=0.0f;
    #pragma unroll
    for (int c=0;c<NC_T;c++){
        float4 p = ((const float4*)ws_part)[(size_t)c*NPIX + pix];
        s+=p.x; a0+=p.y; a1+=p.z; a2+=p.w;
    }
    float invs = 1.0f/s;
    float xa0 = a0*invs, xa1 = a1*invs, xa2 = a2*invs;

    // mlp_out
    float h6[6];
    #pragma unroll
    for (int i=0;i<6;i++){
        float a = mo_w1[i*3+0]*xa0 + mo_w1[i*3+1]*xa1 + mo_w1[i*3+2]*xa2 + mo_b1[i];
        h6[i] = gelu_tanh(a);
    }
    float y[3];
    #pragma unroll
    for (int i=0;i<3;i++){
        float a = mo_b2[i];
        #pragma unroll
        for (int k=0;k<6;k++) a += mo_w2[i*6+k]*h6[k];
        y[i]=a;
    }
    float m  = (y[0]+y[1]+y[2])*(1.0f/3.0f);
    float d0 = y[0]-m, d1 = y[1]-m, d2 = y[2]-m;
    float var = (d0*d0+d1*d1+d2*d2)*(1.0f/3.0f);
    float inv = 1.0f/sqrtf(var+1e-5f);
    float t0 = d0*inv*n2_g[0]+n2_b[0];
    float t1 = d1*inv*n2_g[1]+n2_b[1];
    float t2 = d2*inv*n2_g[2]+n2_b[2];

    // PSF: S_n normalize + blend
    float4 e  = ((const float4*)ws_eehs)[pix*2+0];   // EE, S
    float4 hh = ((const float4*)ws_eehs)[pix*2+1];   // HH
    float Sn = (e.w - mn)/(mx - mn);
    float f0 = Sn*e.x + (1.0f-Sn)*hh.x;
    float f1 = Sn*e.y + (1.0f-Sn)*hh.y;
    float f2 = Sn*e.z + (1.0f-Sn)*hh.z;

    int pos = pix - b*HW;
    #pragma unroll
    for (int o=0;o<3;o++){
        float val = fuse_b[o]
                  + fuse_w[o*6+0]*t0 + fuse_w[o*6+1]*t1 + fuse_w[o*6+2]*t2
                  + fuse_w[o*6+3]*f0 + fuse_w[o*6+4]*f1 + fuse_w[o*6+5]*f2;
        out[(b*3+o)*HW + pos] = val;
    }
}

extern "C" void kernel_launch(void* const* d_in, const int* in_sizes, int n_in,
                              void* d_out, int out_size, void* d_ws, size_t ws_size,
                              hipStream_t stream) {
    const float* front  = (const float*)d_in[0];
    const float* back   = (const float*)d_in[1];
    // d_in[2] = mask (unused by reference)
    const float* bg     = (const float*)d_in[3];
    const float* mi_w1  = (const float*)d_in[4];
    const float* mi_b1  = (const float*)d_in[5];
    const float* mi_w2  = (const float*)d_in[6];
    const float* mi_b2  = (const float*)d_in[7];
    const float* q_w    = (const float*)d_in[8];
    const float* k_w    = (const float*)d_in[9];
    const float* v_w    = (const float*)d_in[10];
    const float* mo_w1  = (const float*)d_in[11];
    const float* mo_b1  = (const float*)d_in[12];
    const float* mo_w2  = (const float*)d_in[13];
    const float* mo_b2  = (const float*)d_in[14];
    const float* n1_g   = (const float*)d_in[15];
    const float* n1_b   = (const float*)d_in[16];
    const float* n2_g   = (const float*)d_in[17];
    const float* n2_b   = (const float*)d_in[18];
    const float* e_w    = (const float*)d_in[19];
    const float* e_b    = (const float*)d_in[20];
    const float* f_w    = (const float*)d_in[21];
    const float* f_b    = (const float*)d_in[22];
    const float* g_w    = (const float*)d_in[23];
    const float* g_b    = (const float*)d_in[24];
    const float* h_w    = (const float*)d_in[25];
    const float* h_b    = (const float*)d_in[26];
    const float* fuse_w = (const float*)d_in[27];
    const float* fuse_b = (const float*)d_in[28];

    float* ws  = (float*)d_ws;
    float* out = (float*)d_out;

    k1_prep<<<dim3(NPIX/64), 64, 0, stream>>>(
        front, back, bg, mi_w1, mi_b1, mi_w2, mi_b2, q_w, k_w, v_w,
        n1_g, n1_b, e_w, e_b, f_w, f_b, g_w, g_b, h_w, h_b, ws);

    size_t need64 = (size_t)(OFF_PART + 64*NPIX*4) * sizeof(float);
    if (ws_size >= need64){
        // primary: NC=64 (KPC=128): 576 blocks, ~20 MB ws
        k2_attn<128><<<dim3(NPIX/(256*8), 64), 256, 0, stream>>>(ws);
        k3_final<64><<<dim3(NPIX/64), 64, 0, stream>>>(
            ws, mo_w1, mo_b1, mo_w2, mo_b2, n2_g, n2_b, fuse_w, fuse_b, out);
    } else {
        // fallback: NC=32 (KPC=256): 288 blocks, ~10.5 MB ws
        k2_attn<256><<<dim3(NPIX/(256*8), 32), 256, 0, stream>>>(ws);
        k3_final<32><<<dim3(NPIX/64), 64, 0, stream>>>(
            ws, mo_w1, mo_b1, mo_w2, mo_b2, n2_g, n2_b, fuse_w, fuse_b, out);
    }
}

// Round 5
// 67.294 us; speedup vs baseline: 1.9147x; 1.1701x over previous
//
#include <hip/hip_runtime.h>
#include <math.h>

#define HW    9216      // 96*96
#define NPIX  18432     // B*HW
#define NKEY  8192

// ws layout (float units)
#define OFF_Q    0                      // [NPIX][4]
#define OFF_KV   (OFF_Q + NPIX*4)       // [NKEY/2 pairs][12] packed pair-transposed
#define OFF_EEHS (OFF_KV + NKEY*6)      // [NPIX][8]  : EE0..2,S | HH0..2,pad
#define OFF_MM   (OFF_EEHS + NPIX*8)    // [288][2]   : per-wave S min,max
#define OFF_PART (OFF_MM + 576)         // [NC][NPIX][4] : s, sv0, sv1, sv2
#define OFF_H    OFF_PART               // k1a->k1b h-planes [12][NPIX], dead before k2 writes

#if __has_builtin(__builtin_amdgcn_exp2f)
#define EXP2(x) __builtin_amdgcn_exp2f(x)
#else
#define EXP2(x) exp2f(x)
#endif

typedef float f32x2 __attribute__((ext_vector_type(2)));
#define FMA2(a,b,c) __builtin_elementwise_fma(a,b,c)

__device__ __forceinline__ float gelu_tanh(float x){
    float u = 0.7978845608028654f*(x + 0.044715f*x*x*x);
    return 0.5f*x*(1.0f + tanhf(u));
}

// ---------------- k1a: kv codebook (packed pairs) + horizontal box sums ----------------
__global__ __launch_bounds__(64) void k1a_prep(
    const float* __restrict__ front, const float* __restrict__ back,
    const float* __restrict__ bg,
    const float* __restrict__ k_w,  const float* __restrict__ v_w,
    float* __restrict__ ws)
{
    float* ws_kv = ws + OFF_KV;
    float* ws_h  = ws + OFF_H;

    int tid = threadIdx.x;
    int pix = blockIdx.x*64 + tid;      // 0..18431

    // ---------- keys: pack pair-transposed: A=(kx0,kx1,ky0,ky1) B=(kz0,kz1,v00,v01) C=(v10,v11,v20,v21)
    if (pix < NKEY/2){
        int p = pix;
        float e00=bg[2*p],        e01=bg[2*p+1];
        float e10=bg[NKEY+2*p],   e11=bg[NKEY+2*p+1];
        float e20=bg[2*NKEY+2*p], e21=bg[2*NKEY+2*p+1];
        float k0[3], k1[3], w0[3], w1[3];
        #pragma unroll
        for (int i=0;i<3;i++){
            k0[i] = k_w[i*3+0]*e00 + k_w[i*3+1]*e10 + k_w[i*3+2]*e20;
            k1[i] = k_w[i*3+0]*e01 + k_w[i*3+1]*e11 + k_w[i*3+2]*e21;
            w0[i] = v_w[i*3+0]*e00 + v_w[i*3+1]*e10 + v_w[i*3+2]*e20;
            w1[i] = v_w[i*3+0]*e01 + v_w[i*3+1]*e11 + v_w[i*3+2]*e21;
        }
        float4* kv4 = (float4*)ws_kv;
        kv4[p*3+0] = make_float4(k0[0],k1[0],k0[1],k1[1]);
        kv4[p*3+1] = make_float4(k0[2],k1[2],w0[0],w1[0]);
        kv4[p*3+2] = make_float4(w0[1],w1[1],w0[2],w1[2]);
    }

    int b   = (pix >= HW) ? 1 : 0;
    int pos = pix - b*HW;
    int y   = pos / 96;
    int x   = pos - y*96;
    const float* fbase = front + b*3*HW;
    const float* bbase = back  + b*3*HW;
    int row = y*96;

    float fs1[3]={0,0,0}, fs2[3]={0,0,0}, bs1[3]={0,0,0}, bs2[3]={0,0,0};
    #pragma unroll
    for (int dx=-3; dx<=3; ++dx){
        int xx = x+dx;
        float ok = ((unsigned)xx < 96u) ? 1.0f : 0.0f;
        int xc = xx < 0 ? 0 : (xx > 95 ? 95 : xx);
        #pragma unroll
        for (int c=0;c<3;c++){
            float fv = fbase[c*HW + row + xc]*ok;
            float bv = bbase[c*HW + row + xc]*ok;
            fs1[c]+=fv; fs2[c]+=fv*fv;
            bs1[c]+=bv; bs2[c]+=bv*bv;
        }
    }
    #pragma unroll
    for (int c=0;c<3;c++){
        ws_h[(c  )*NPIX + pix] = fs1[c];
        ws_h[(3+c)*NPIX + pix] = fs2[c];
        ws_h[(6+c)*NPIX + pix] = bs1[c];
        ws_h[(9+c)*NPIX + pix] = bs2[c];
    }
}

// ---------------- k1b: vertical box sums + PSF per-pixel + q tokens ----------------
__global__ __launch_bounds__(64) void k1b_prep(
    const float* __restrict__ front, const float* __restrict__ back,
    const float* __restrict__ mi_w1, const float* __restrict__ mi_b1,
    const float* __restrict__ mi_w2, const float* __restrict__ mi_b2,
    const float* __restrict__ q_w,
    const float* __restrict__ n1_g, const float* __restrict__ n1_b,
    const float* __restrict__ e_w,  const float* __restrict__ e_b,
    const float* __restrict__ f_w,  const float* __restrict__ f_b,
    const float* __restrict__ g_w,  const float* __restrict__ g_b,
    const float* __restrict__ h_w,  const float* __restrict__ h_b,
    float* __restrict__ ws)
{
    float* ws_q    = ws + OFF_Q;
    float* ws_eehs = ws + OFF_EEHS;
    float* ws_mm   = ws + OFF_MM;
    const float* ws_h = ws + OFF_H;

    int tid = threadIdx.x;
    int pix = blockIdx.x*64 + tid;
    int b   = (pix >= HW) ? 1 : 0;
    int pos = pix - b*HW;
    int y   = pos / 96;
    const float* fbase = front + b*3*HW;
    const float* bbase = back  + b*3*HW;

    float s1f[3]={0,0,0}, s2f[3]={0,0,0}, s1b[3]={0,0,0}, s2b[3]={0,0,0};
    #pragma unroll
    for (int dy=-3; dy<=3; ++dy){
        int yy = y+dy;
        float ok = ((unsigned)yy < 96u) ? 1.0f : 0.0f;
        int dyc = yy < 0 ? -y : (yy > 95 ? 95-y : dy);
        int off = pix + dyc*96;
        #pragma unroll
        for (int c=0;c<3;c++){
            s1f[c] += ws_h[(c  )*NPIX + off]*ok;
            s2f[c] += ws_h[(3+c)*NPIX + off]*ok;
            s1b[c] += ws_h[(6+c)*NPIX + off]*ok;
            s2b[c] += ws_h[(9+c)*NPIX + off]*ok;
        }
    }

    float xnf[3], adain[3], bn[3], bval[3];
    #pragma unroll
    for (int c=0;c<3;c++){
        float mf = s1f[c]*(1.0f/49.0f);
        float vf = (s2f[c] - s1f[c]*s1f[c]*(1.0f/49.0f))*(1.0f/48.0f);
        float fv = fbase[c*HW+pos];
        xnf[c] = (fv - mf)/(sqrtf(vf)+1e-8f);

        float mb = s1b[c]*(1.0f/49.0f);
        float vb = (s2b[c] - s1b[c]*s1b[c]*(1.0f/49.0f))*(1.0f/48.0f);
        float bb = bbase[c*HW+pos];
        bval[c]  = bb;
        float stdb = sqrtf(vb);
        adain[c] = xnf[c]*stdb + mb;         // no eps on y_std
        bn[c]    = (bb - mb)/(stdb + 1e-8f);
    }

    float EE[3], FF[3], GG[3], HHv[3];
    #pragma unroll
    for (int i=0;i<3;i++){
        EE[i]  = e_w[i*3+0]*adain[0] + e_w[i*3+1]*adain[1] + e_w[i*3+2]*adain[2] + e_b[i];
        FF[i]  = f_w[i*3+0]*xnf[0]   + f_w[i*3+1]*xnf[1]   + f_w[i*3+2]*xnf[2]   + f_b[i];
        GG[i]  = g_w[i*3+0]*bn[0]    + g_w[i*3+1]*bn[1]    + g_w[i*3+2]*bn[2]    + g_b[i];
        HHv[i] = h_w[i*3+0]*bval[0]  + h_w[i*3+1]*bval[1]  + h_w[i*3+2]*bval[2]  + h_b[i];
    }
    float num = FF[0]*GG[0]+FF[1]*GG[1]+FF[2]*GG[2];
    float fn  = sqrtf(FF[0]*FF[0]+FF[1]*FF[1]+FF[2]*FF[2]);
    float gn  = sqrtf(GG[0]*GG[0]+GG[1]*GG[1]+GG[2]*GG[2]);
    float S   = num/(fn*gn);

    float4* eehs4 = (float4*)ws_eehs;
    eehs4[pix*2+0] = make_float4(EE[0],EE[1],EE[2],S);
    eehs4[pix*2+1] = make_float4(HHv[0],HHv[1],HHv[2],0.0f);

    // per-wave S min/max (block == 1 wave)
    float mn = S, mx = S;
    #pragma unroll
    for (int off=32; off>0; off>>=1){
        mn = fminf(mn, __shfl_xor(mn, off));
        mx = fmaxf(mx, __shfl_xor(mx, off));
    }
    if (tid==0){ ws_mm[blockIdx.x*2+0]=mn; ws_mm[blockIdx.x*2+1]=mx; }

    // token q : mlp_in -> ln -> q_w, pre-scaled by scale*log2e
    float xt0 = fbase[0*HW+pos], xt1 = fbase[1*HW+pos], xt2 = fbase[2*HW+pos];
    float h6[6];
    #pragma unroll
    for (int i=0;i<6;i++){
        float a = mi_w1[i*3+0]*xt0 + mi_w1[i*3+1]*xt1 + mi_w1[i*3+2]*xt2 + mi_b1[i];
        h6[i] = gelu_tanh(a);
    }
    float x2[3];
    #pragma unroll
    for (int i=0;i<3;i++){
        float a = mi_b2[i];
        #pragma unroll
        for (int k=0;k<6;k++) a += mi_w2[i*6+k]*h6[k];
        x2[i]=a;
    }
    float m  = (x2[0]+x2[1]+x2[2])*(1.0f/3.0f);
    float d0 = x2[0]-m, d1 = x2[1]-m, d2 = x2[2]-m;
    float var = (d0*d0+d1*d1+d2*d2)*(1.0f/3.0f);
    float inv = 1.0f/sqrtf(var+1e-5f);
    float xn0 = d0*inv*n1_g[0]+n1_b[0];
    float xn1 = d1*inv*n1_g[1]+n1_b[1];
    float xn2 = d2*inv*n1_g[2]+n1_b[2];
    const float qs = 0.5773502691896258f * 1.4426950408889634f; // d^-0.5 * log2(e)
    float4 qv;
    qv.x = (q_w[0]*xn0 + q_w[1]*xn1 + q_w[2]*xn2)*qs;
    qv.y = (q_w[3]*xn0 + q_w[4]*xn1 + q_w[5]*xn2)*qs;
    qv.z = (q_w[6]*xn0 + q_w[7]*xn1 + q_w[8]*xn2)*qs;
    qv.w = 0.0f;
    ((float4*)ws_q)[pix] = qv;
}

// ---------------- k2: packed-f32 pairs, 8 queries/thread, named scalars ----------------

#define DECLQ(J) f32x2 qx##J, qy##J, qz##J; \
                 f32x2 s##J={0.f,0.f}, a0##J={0.f,0.f}, a1##J={0.f,0.f}, a2##J={0.f,0.f};

#define LOADQ(J) { float4 qq = q4[qbase + J*256]; \
                   qx##J = (f32x2){qq.x,qq.x}; qy##J = (f32x2){qq.y,qq.y}; qz##J = (f32x2){qq.z,qq.z}; }

#define QSTEP(J) { \
    f32x2 l = FMA2(qz##J, kz, FMA2(qy##J, ky, qx##J*kx)); \
    f32x2 p; p.x = EXP2(l.x); p.y = EXP2(l.y); \
    s##J += p; \
    a0##J = FMA2(p, v0, a0##J); \
    a1##J = FMA2(p, v1, a1##J); \
    a2##J = FMA2(p, v2, a2##J); }

#define STOREP(J) dst[J*256] = make_float4(s##J.x+s##J.y, a0##J.x+a0##J.y, a1##J.x+a1##J.y, a2##J.x+a2##J.y);

template<int KPC_T>
__global__ __launch_bounds__(256) void k2_attn(const float* __restrict__ ws)
{
    const float* ws_q  = ws + OFF_Q;
    const float* ws_kv = ws + OFF_KV;
    float* ws_part     = (float*)(ws + OFF_PART);

    constexpr int PP = KPC_T/2;            // key pairs per chunk
    __shared__ float4 lkv[PP*3];
    int tid   = threadIdx.x;
    int chunk = blockIdx.y;
    const float4* src = (const float4*)ws_kv + (size_t)chunk*PP*3;
    for (int i=tid; i<PP*3; i+=256) lkv[i]=src[i];
    __syncthreads();

    const float4* q4 = (const float4*)ws_q;
    int qbase = blockIdx.x*(256*8) + tid;   // strided by 256 across 8 queries

    DECLQ(0) DECLQ(1) DECLQ(2) DECLQ(3)
    DECLQ(4) DECLQ(5) DECLQ(6) DECLQ(7)
    LOADQ(0) LOADQ(1) LOADQ(2) LOADQ(3)
    LOADQ(4) LOADQ(5) LOADQ(6) LOADQ(7)

    for (int kk=0; kk<PP; ++kk){
        float4 A = lkv[kk*3+0];
        float4 B = lkv[kk*3+1];
        float4 C = lkv[kk*3+2];
        f32x2 kx = (f32x2){A.x,A.y}, ky = (f32x2){A.z,A.w}, kz = (f32x2){B.x,B.y};
        f32x2 v0 = (f32x2){B.z,B.w}, v1 = (f32x2){C.x,C.y}, v2 = (f32x2){C.z,C.w};
        QSTEP(0) QSTEP(1) QSTEP(2) QSTEP(3)
        QSTEP(4) QSTEP(5) QSTEP(6) QSTEP(7)
    }

    float4* dst = (float4*)ws_part + (size_t)chunk*NPIX + qbase;
    STOREP(0) STOREP(1) STOREP(2) STOREP(3)
    STOREP(4) STOREP(5) STOREP(6) STOREP(7)
}

// ---------------- k3: merge partials + mlp_out + ln + PSF blend + fuse ----------------
template<int NC_T>
__global__ __launch_bounds__(64) void k3_final(
    const float* __restrict__ ws,
    const float* __restrict__ mo_w1, const float* __restrict__ mo_b1,
    const float* __restrict__ mo_w2, const float* __restrict__ mo_b2,
    const float* __restrict__ n2_g,  const float* __restrict__ n2_b,
    const float* __restrict__ fuse_w,const float* __restrict__ fuse_b,
    float* __restrict__ out)
{
    const float* ws_eehs = ws + OFF_EEHS;
    const float* ws_mm   = ws + OFF_MM;
    const float* ws_part = ws + OFF_PART;

    int tid = threadIdx.x;
    int pix = blockIdx.x*64 + tid;
    int b   = (pix >= HW) ? 1 : 0;

    // batch S min/max: wave-cooperative over 144 wave entries
    int base = b*144;
    float mn = INFINITY, mx = -INFINITY;
    for (int i=tid; i<144; i+=64){
        mn = fminf(mn, ws_mm[(base+i)*2+0]);
        mx = fmaxf(mx, ws_mm[(base+i)*2+1]);
    }
    #pragma unroll
    for (int off=32; off>0; off>>=1){
        mn = fminf(mn, __shfl_xor(mn, off));
        mx = fmaxf(mx, __shfl_xor(mx, off));
    }

    // merge attention partials
    float s=0.0f, a0=0.0f, a1=0.0f, a2=0.0f;
    #pragma unroll 8
    for (int c=0;c<NC_T;c++){
        float4 p = ((const float4*)ws_part)[(size_t)c*NPIX + pix];
        s+=p.x; a0+=p.y; a1+=p.z; a2+=p.w;
    }
    float invs = 1.0f/s;
    float xa0 = a0*invs, xa1 = a1*invs, xa2 = a2*invs;

    // mlp_out
    float h6[6];
    #pragma unroll
    for (int i=0;i<6;i++){
        float a = mo_w1[i*3+0]*xa0 + mo_w1[i*3+1]*xa1 + mo_w1[i*3+2]*xa2 + mo_b1[i];
        h6[i] = gelu_tanh(a);
    }
    float y[3];
    #pragma unroll
    for (int i=0;i<3;i++){
        float a = mo_b2[i];
        #pragma unroll
        for (int k=0;k<6;k++) a += mo_w2[i*6+k]*h6[k];
        y[i]=a;
    }
    float m  = (y[0]+y[1]+y[2])*(1.0f/3.0f);
    float d0 = y[0]-m, d1 = y[1]-m, d2 = y[2]-m;
    float var = (d0*d0+d1*d1+d2*d2)*(1.0f/3.0f);
    float inv = 1.0f/sqrtf(var+1e-5f);
    float t0 = d0*inv*n2_g[0]+n2_b[0];
    float t1 = d1*inv*n2_g[1]+n2_b[1];
    float t2 = d2*inv*n2_g[2]+n2_b[2];

    // PSF: S_n normalize + blend
    float4 e  = ((const float4*)ws_eehs)[pix*2+0];   // EE, S
    float4 hh = ((const float4*)ws_eehs)[pix*2+1];   // HH
    float Sn = (e.w - mn)/(mx - mn);
    float f0 = Sn*e.x + (1.0f-Sn)*hh.x;
    float f1 = Sn*e.y + (1.0f-Sn)*hh.y;
    float f2 = Sn*e.z + (1.0f-Sn)*hh.z;

    int pos = pix - b*HW;
    #pragma unroll
    for (int o=0;o<3;o++){
        float val = fuse_b[o]
                  + fuse_w[o*6+0]*t0 + fuse_w[o*6+1]*t1 + fuse_w[o*6+2]*t2
                  + fuse_w[o*6+3]*f0 + fuse_w[o*6+4]*f1 + fuse_w[o*6+5]*f2;
        out[(b*3+o)*HW + pos] = val;
    }
}

extern "C" void kernel_launch(void* const* d_in, const int* in_sizes, int n_in,
                              void* d_out, int out_size, void* d_ws, size_t ws_size,
                              hipStream_t stream) {
    const float* front  = (const float*)d_in[0];
    const float* back   = (const float*)d_in[1];
    // d_in[2] = mask (unused by reference)
    const float* bg     = (const float*)d_in[3];
    const float* mi_w1  = (const float*)d_in[4];
    const float* mi_b1  = (const float*)d_in[5];
    const float* mi_w2  = (const float*)d_in[6];
    const float* mi_b2  = (const float*)d_in[7];
    const float* q_w    = (const float*)d_in[8];
    const float* k_w    = (const float*)d_in[9];
    const float* v_w    = (const float*)d_in[10];
    const float* mo_w1  = (const float*)d_in[11];
    const float* mo_b1  = (const float*)d_in[12];
    const float* mo_w2  = (const float*)d_in[13];
    const float* mo_b2  = (const float*)d_in[14];
    const float* n1_g   = (const float*)d_in[15];
    const float* n1_b   = (const float*)d_in[16];
    const float* n2_g   = (const float*)d_in[17];
    const float* n2_b   = (const float*)d_in[18];
    const float* e_w    = (const float*)d_in[19];
    const float* e_b    = (const float*)d_in[20];
    const float* f_w    = (const float*)d_in[21];
    const float* f_b    = (const float*)d_in[22];
    const float* g_w    = (const float*)d_in[23];
    const float* g_b    = (const float*)d_in[24];
    const float* h_w    = (const float*)d_in[25];
    const float* h_b    = (const float*)d_in[26];
    const float* fuse_w = (const float*)d_in[27];
    const float* fuse_b = (const float*)d_in[28];

    float* ws  = (float*)d_ws;
    float* out = (float*)d_out;

    k1a_prep<<<dim3(NPIX/64), 64, 0, stream>>>(front, back, bg, k_w, v_w, ws);

    k1b_prep<<<dim3(NPIX/64), 64, 0, stream>>>(
        front, back, mi_w1, mi_b1, mi_w2, mi_b2, q_w,
        n1_g, n1_b, e_w, e_b, f_w, f_b, g_w, g_b, h_w, h_b, ws);

    size_t need128 = (size_t)(OFF_PART + 128*NPIX*4) * sizeof(float);
    if (ws_size >= need128){
        // primary: NC=128 (KPC=64): 1152 blocks, 18 waves/CU, ~39 MB ws
        k2_attn<64><<<dim3(NPIX/(256*8), 128), 256, 0, stream>>>(ws);
        k3_final<128><<<dim3(NPIX/64), 64, 0, stream>>>(
            ws, mo_w1, mo_b1, mo_w2, mo_b2, n2_g, n2_b, fuse_w, fuse_b, out);
    } else {
        // fallback: NC=64 (KPC=128): 576 blocks, ~20 MB ws (verified fits in prior rounds)
        k2_attn<128><<<dim3(NPIX/(256*8), 64), 256, 0, stream>>>(ws);
        k3_final<64><<<dim3(NPIX/64), 64, 0, stream>>>(
            ws, mo_w1, mo_b1, mo_w2, mo_b2, n2_g, n2_b, fuse_w, fuse_b, out);
    }
}

// Round 6
// 66.551 us; speedup vs baseline: 1.9361x; 1.0112x over previous
//
#include <hip/hip_runtime.h>
#include <math.h>

#define HW    9216      // 96*96
#define NPIX  18432     // B*HW
#define NKEY  8192

// ws layout (float units)
#define OFF_Q    0                      // [NPIX][4]
#define OFF_KV   (OFF_Q + NPIX*4)       // [NKEY/2 pairs][12] packed pair-transposed
#define OFF_EEHS (OFF_KV + NKEY*6)      // [NPIX][8]  : EE0..2,S | HH0..2,pad
#define OFF_MM   (OFF_EEHS + NPIX*8)    // [288][2]   : per-wave S min,max (72 blocks x 4 waves)
#define OFF_PART (OFF_MM + 576)         // [NC][NPIX][4] : s, sv0, sv1, sv2

#if __has_builtin(__builtin_amdgcn_exp2f)
#define EXP2(x) __builtin_amdgcn_exp2f(x)
#else
#define EXP2(x) exp2f(x)
#endif

typedef float f32x2 __attribute__((ext_vector_type(2)));
#define FMA2(a,b,c) __builtin_elementwise_fma(a,b,c)

__device__ __forceinline__ float gelu_tanh(float x){
    float u = 0.7978845608028654f*(x + 0.044715f*x*x*x);
    return 0.5f*x*(1.0f + tanhf(u));
}

// ---------------- k1: fused prep. 72 blocks x 256 threads, 16x16 output tile each ----------------
// LDS-staged 22x22 halo (zero-padded), 7x7 box stats from LDS, PSF per-pixel, q tokens,
// per-wave S min/max, and kv codebook packing folded into blocks 0..15.
__global__ __launch_bounds__(256) void k1_prep(
    const float* __restrict__ front, const float* __restrict__ back,
    const float* __restrict__ bg,
    const float* __restrict__ k_w,  const float* __restrict__ v_w,
    const float* __restrict__ mi_w1, const float* __restrict__ mi_b1,
    const float* __restrict__ mi_w2, const float* __restrict__ mi_b2,
    const float* __restrict__ q_w,
    const float* __restrict__ n1_g, const float* __restrict__ n1_b,
    const float* __restrict__ e_w,  const float* __restrict__ e_b,
    const float* __restrict__ f_w,  const float* __restrict__ f_b,
    const float* __restrict__ g_w,  const float* __restrict__ g_b,
    const float* __restrict__ h_w,  const float* __restrict__ h_b,
    float* __restrict__ ws)
{
    float* ws_q    = ws + OFF_Q;
    float* ws_kv   = ws + OFF_KV;
    float* ws_eehs = ws + OFF_EEHS;
    float* ws_mm   = ws + OFF_MM;

    __shared__ float lds[6][484];        // 22x22 halo, planes: f0,f1,f2,b0,b1,b2

    int tid = threadIdx.x;
    int bid = blockIdx.x;                // 0..71
    int img = bid / 36;
    int t   = bid % 36;
    int ty  = (t / 6) * 16;
    int tx  = (t % 6) * 16;

    // ---------- kv codebook packing (blocks 0..15 handle 4096 key-pairs) ----------
    if (bid < 16){
        int p = bid*256 + tid;           // pair index 0..4095
        float e00=bg[2*p],        e01=bg[2*p+1];
        float e10=bg[NKEY+2*p],   e11=bg[NKEY+2*p+1];
        float e20=bg[2*NKEY+2*p], e21=bg[2*NKEY+2*p+1];
        float k0[3], k1[3], w0[3], w1[3];
        #pragma unroll
        for (int i=0;i<3;i++){
            k0[i] = k_w[i*3+0]*e00 + k_w[i*3+1]*e10 + k_w[i*3+2]*e20;
            k1[i] = k_w[i*3+0]*e01 + k_w[i*3+1]*e11 + k_w[i*3+2]*e21;
            w0[i] = v_w[i*3+0]*e00 + v_w[i*3+1]*e10 + v_w[i*3+2]*e20;
            w1[i] = v_w[i*3+0]*e01 + v_w[i*3+1]*e11 + v_w[i*3+2]*e21;
        }
        float4* kv4 = (float4*)ws_kv;
        kv4[p*3+0] = make_float4(k0[0],k1[0],k0[1],k1[1]);
        kv4[p*3+1] = make_float4(k0[2],k1[2],w0[0],w1[0]);
        kv4[p*3+2] = make_float4(w0[1],w1[1],w0[2],w1[2]);
    }

    const float* fbase = front + img*3*HW;
    const float* bbase = back  + img*3*HW;

    // ---------- stage 22x22 halo (zero-padded) for 6 planes ----------
    for (int i = tid; i < 484; i += 256){
        int hy = i / 22, hx = i - hy*22;
        int gy = ty + hy - 3, gx = tx + hx - 3;
        bool ok = ((unsigned)gy < 96u) && ((unsigned)gx < 96u);
        int off = gy*96 + gx;
        #pragma unroll
        for (int c=0;c<3;c++){
            lds[c  ][i] = ok ? fbase[c*HW+off] : 0.0f;
            lds[3+c][i] = ok ? bbase[c*HW+off] : 0.0f;
        }
    }
    __syncthreads();

    int ly = tid / 16, lx = tid - ly*16;
    int y  = ty + ly,  x  = tx + lx;
    int pos = y*96 + x;
    int pix = img*HW + pos;

    // ---------- 7x7 box stats from LDS ----------
    float s1f[3]={0,0,0}, s2f[3]={0,0,0}, s1b[3]={0,0,0}, s2b[3]={0,0,0};
    #pragma unroll
    for (int dy=0; dy<7; ++dy){
        int rb = (ly+dy)*22 + lx;
        #pragma unroll
        for (int dx=0; dx<7; ++dx){
            #pragma unroll
            for (int c=0;c<3;c++){
                float fv = lds[c  ][rb+dx];
                float bv = lds[3+c][rb+dx];
                s1f[c]+=fv; s2f[c]+=fv*fv;
                s1b[c]+=bv; s2b[c]+=bv*bv;
            }
        }
    }

    int ctr = (ly+3)*22 + (lx+3);
    float xnf[3], adain[3], bn[3], bval[3], fctr[3];
    #pragma unroll
    for (int c=0;c<3;c++){
        float mf = s1f[c]*(1.0f/49.0f);
        float vf = (s2f[c] - s1f[c]*s1f[c]*(1.0f/49.0f))*(1.0f/48.0f);
        float fv = lds[c][ctr];
        fctr[c] = fv;
        xnf[c] = (fv - mf)/(sqrtf(vf)+1e-8f);

        float mb = s1b[c]*(1.0f/49.0f);
        float vb = (s2b[c] - s1b[c]*s1b[c]*(1.0f/49.0f))*(1.0f/48.0f);
        float bb = lds[3+c][ctr];
        bval[c]  = bb;
        float stdb = sqrtf(vb);
        adain[c] = xnf[c]*stdb + mb;         // no eps on y_std
        bn[c]    = (bb - mb)/(stdb + 1e-8f);
    }

    float EE[3], FF[3], GG[3], HHv[3];
    #pragma unroll
    for (int i=0;i<3;i++){
        EE[i]  = e_w[i*3+0]*adain[0] + e_w[i*3+1]*adain[1] + e_w[i*3+2]*adain[2] + e_b[i];
        FF[i]  = f_w[i*3+0]*xnf[0]   + f_w[i*3+1]*xnf[1]   + f_w[i*3+2]*xnf[2]   + f_b[i];
        GG[i]  = g_w[i*3+0]*bn[0]    + g_w[i*3+1]*bn[1]    + g_w[i*3+2]*bn[2]    + g_b[i];
        HHv[i] = h_w[i*3+0]*bval[0]  + h_w[i*3+1]*bval[1]  + h_w[i*3+2]*bval[2]  + h_b[i];
    }
    float num = FF[0]*GG[0]+FF[1]*GG[1]+FF[2]*GG[2];
    float fn  = sqrtf(FF[0]*FF[0]+FF[1]*FF[1]+FF[2]*FF[2]);
    float gn  = sqrtf(GG[0]*GG[0]+GG[1]*GG[1]+GG[2]*GG[2]);
    float S   = num/(fn*gn);

    float4* eehs4 = (float4*)ws_eehs;
    eehs4[pix*2+0] = make_float4(EE[0],EE[1],EE[2],S);
    eehs4[pix*2+1] = make_float4(HHv[0],HHv[1],HHv[2],0.0f);

    // ---------- per-wave S min/max (4 waves per block; entries bid*4+wave, 144 per img) ----------
    float mn = S, mx = S;
    #pragma unroll
    for (int off=32; off>0; off>>=1){
        mn = fminf(mn, __shfl_xor(mn, off));
        mx = fmaxf(mx, __shfl_xor(mx, off));
    }
    if ((tid & 63) == 0){
        int entry = bid*4 + (tid>>6);
        ws_mm[entry*2+0]=mn; ws_mm[entry*2+1]=mx;
    }

    // ---------- token q : mlp_in -> ln -> q_w, pre-scaled by scale*log2e ----------
    float xt0 = fctr[0], xt1 = fctr[1], xt2 = fctr[2];
    float h6[6];
    #pragma unroll
    for (int i=0;i<6;i++){
        float a = mi_w1[i*3+0]*xt0 + mi_w1[i*3+1]*xt1 + mi_w1[i*3+2]*xt2 + mi_b1[i];
        h6[i] = gelu_tanh(a);
    }
    float x2[3];
    #pragma unroll
    for (int i=0;i<3;i++){
        float a = mi_b2[i];
        #pragma unroll
        for (int k=0;k<6;k++) a += mi_w2[i*6+k]*h6[k];
        x2[i]=a;
    }
    float m  = (x2[0]+x2[1]+x2[2])*(1.0f/3.0f);
    float d0 = x2[0]-m, d1 = x2[1]-m, d2 = x2[2]-m;
    float var = (d0*d0+d1*d1+d2*d2)*(1.0f/3.0f);
    float inv = 1.0f/sqrtf(var+1e-5f);
    float xn0 = d0*inv*n1_g[0]+n1_b[0];
    float xn1 = d1*inv*n1_g[1]+n1_b[1];
    float xn2 = d2*inv*n1_g[2]+n1_b[2];
    const float qs = 0.5773502691896258f * 1.4426950408889634f; // d^-0.5 * log2(e)
    float4 qv;
    qv.x = (q_w[0]*xn0 + q_w[1]*xn1 + q_w[2]*xn2)*qs;
    qv.y = (q_w[3]*xn0 + q_w[4]*xn1 + q_w[5]*xn2)*qs;
    qv.z = (q_w[6]*xn0 + q_w[7]*xn1 + q_w[8]*xn2)*qs;
    qv.w = 0.0f;
    ((float4*)ws_q)[pix] = qv;
}

// ---------------- k2: packed-f32 pairs, 8 queries/thread, named scalars ----------------

#define DECLQ(J) f32x2 qx##J, qy##J, qz##J; \
                 f32x2 s##J={0.f,0.f}, a0##J={0.f,0.f}, a1##J={0.f,0.f}, a2##J={0.f,0.f};

#define LOADQ(J) { float4 qq = q4[qbase + J*256]; \
                   qx##J = (f32x2){qq.x,qq.x}; qy##J = (f32x2){qq.y,qq.y}; qz##J = (f32x2){qq.z,qq.z}; }

#define QSTEP(J) { \
    f32x2 l = FMA2(qz##J, kz, FMA2(qy##J, ky, qx##J*kx)); \
    f32x2 p; p.x = EXP2(l.x); p.y = EXP2(l.y); \
    s##J += p; \
    a0##J = FMA2(p, v0, a0##J); \
    a1##J = FMA2(p, v1, a1##J); \
    a2##J = FMA2(p, v2, a2##J); }

#define STOREP(J) dst[J*256] = make_float4(s##J.x+s##J.y, a0##J.x+a0##J.y, a1##J.x+a1##J.y, a2##J.x+a2##J.y);

template<int KPC_T>
__global__ __launch_bounds__(256) void k2_attn(const float* __restrict__ ws)
{
    const float* ws_q  = ws + OFF_Q;
    const float* ws_kv = ws + OFF_KV;
    float* ws_part     = (float*)(ws + OFF_PART);

    constexpr int PP = KPC_T/2;            // key pairs per chunk
    __shared__ float4 lkv[PP*3];
    int tid   = threadIdx.x;
    int chunk = blockIdx.y;
    const float4* src = (const float4*)ws_kv + (size_t)chunk*PP*3;
    for (int i=tid; i<PP*3; i+=256) lkv[i]=src[i];
    __syncthreads();

    const float4* q4 = (const float4*)ws_q;
    int qbase = blockIdx.x*(256*8) + tid;   // strided by 256 across 8 queries

    DECLQ(0) DECLQ(1) DECLQ(2) DECLQ(3)
    DECLQ(4) DECLQ(5) DECLQ(6) DECLQ(7)
    LOADQ(0) LOADQ(1) LOADQ(2) LOADQ(3)
    LOADQ(4) LOADQ(5) LOADQ(6) LOADQ(7)

    for (int kk=0; kk<PP; ++kk){
        float4 A = lkv[kk*3+0];
        float4 B = lkv[kk*3+1];
        float4 C = lkv[kk*3+2];
        f32x2 kx = (f32x2){A.x,A.y}, ky = (f32x2){A.z,A.w}, kz = (f32x2){B.x,B.y};
        f32x2 v0 = (f32x2){B.z,B.w}, v1 = (f32x2){C.x,C.y}, v2 = (f32x2){C.z,C.w};
        QSTEP(0) QSTEP(1) QSTEP(2) QSTEP(3)
        QSTEP(4) QSTEP(5) QSTEP(6) QSTEP(7)
    }

    float4* dst = (float4*)ws_part + (size_t)chunk*NPIX + qbase;
    STOREP(0) STOREP(1) STOREP(2) STOREP(3)
    STOREP(4) STOREP(5) STOREP(6) STOREP(7)
}

// ---------------- k3: merge partials + mlp_out + ln + PSF blend + fuse (72 blocks x 256) ----------------
template<int NC_T>
__global__ __launch_bounds__(256) void k3_final(
    const float* __restrict__ ws,
    const float* __restrict__ mo_w1, const float* __restrict__ mo_b1,
    const float* __restrict__ mo_w2, const float* __restrict__ mo_b2,
    const float* __restrict__ n2_g,  const float* __restrict__ n2_b,
    const float* __restrict__ fuse_w,const float* __restrict__ fuse_b,
    float* __restrict__ out)
{
    const float* ws_eehs = ws + OFF_EEHS;
    const float* ws_mm   = ws + OFF_MM;
    const float* ws_part = ws + OFF_PART;

    int tid = threadIdx.x;
    int pix = blockIdx.x*256 + tid;
    int b   = (pix >= HW) ? 1 : 0;       // uniform per block (9216 % 256 == 0)

    // ---------- batch S min/max: block-cooperative over 144 wave entries ----------
    __shared__ float wmn[4], wmx[4];
    float mn = INFINITY, mx = -INFINITY;
    if (tid < 144){
        mn = ws_mm[(b*144+tid)*2+0];
        mx = ws_mm[(b*144+tid)*2+1];
    }
    #pragma unroll
    for (int off=32; off>0; off>>=1){
        mn = fminf(mn, __shfl_xor(mn, off));
        mx = fmaxf(mx, __shfl_xor(mx, off));
    }
    if ((tid & 63) == 0){ wmn[tid>>6]=mn; wmx[tid>>6]=mx; }
    __syncthreads();
    mn = fminf(fminf(wmn[0],wmn[1]), fminf(wmn[2],wmn[3]));
    mx = fmaxf(fmaxf(wmx[0],wmx[1]), fmaxf(wmx[2],wmx[3]));

    // ---------- merge attention partials ----------
    float s=0.0f, a0=0.0f, a1=0.0f, a2=0.0f;
    #pragma unroll 8
    for (int c=0;c<NC_T;c++){
        float4 p = ((const float4*)ws_part)[(size_t)c*NPIX + pix];
        s+=p.x; a0+=p.y; a1+=p.z; a2+=p.w;
    }
    float invs = 1.0f/s;
    float xa0 = a0*invs, xa1 = a1*invs, xa2 = a2*invs;

    // mlp_out
    float h6[6];
    #pragma unroll
    for (int i=0;i<6;i++){
        float a = mo_w1[i*3+0]*xa0 + mo_w1[i*3+1]*xa1 + mo_w1[i*3+2]*xa2 + mo_b1[i];
        h6[i] = gelu_tanh(a);
    }
    float y[3];
    #pragma unroll
    for (int i=0;i<3;i++){
        float a = mo_b2[i];
        #pragma unroll
        for (int k=0;k<6;k++) a += mo_w2[i*6+k]*h6[k];
        y[i]=a;
    }
    float m  = (y[0]+y[1]+y[2])*(1.0f/3.0f);
    float d0 = y[0]-m, d1 = y[1]-m, d2 = y[2]-m;
    float var = (d0*d0+d1*d1+d2*d2)*(1.0f/3.0f);
    float inv = 1.0f/sqrtf(var+1e-5f);
    float t0 = d0*inv*n2_g[0]+n2_b[0];
    float t1 = d1*inv*n2_g[1]+n2_b[1];
    float t2 = d2*inv*n2_g[2]+n2_b[2];

    // PSF: S_n normalize + blend
    float4 e  = ((const float4*)ws_eehs)[pix*2+0];   // EE, S
    float4 hh = ((const float4*)ws_eehs)[pix*2+1];   // HH
    float Sn = (e.w - mn)/(mx - mn);
    float f0 = Sn*e.x + (1.0f-Sn)*hh.x;
    float f1 = Sn*e.y + (1.0f-Sn)*hh.y;
    float f2 = Sn*e.z + (1.0f-Sn)*hh.z;

    int pos = pix - b*HW;
    #pragma unroll
    for (int o=0;o<3;o++){
        float val = fuse_b[o]
                  + fuse_w[o*6+0]*t0 + fuse_w[o*6+1]*t1 + fuse_w[o*6+2]*t2
                  + fuse_w[o*6+3]*f0 + fuse_w[o*6+4]*f1 + fuse_w[o*6+5]*f2;
        out[(b*3+o)*HW + pos] = val;
    }
}

extern "C" void kernel_launch(void* const* d_in, const int* in_sizes, int n_in,
                              void* d_out, int out_size, void* d_ws, size_t ws_size,
                              hipStream_t stream) {
    const float* front  = (const float*)d_in[0];
    const float* back   = (const float*)d_in[1];
    // d_in[2] = mask (unused by reference)
    const float* bg     = (const float*)d_in[3];
    const float* mi_w1  = (const float*)d_in[4];
    const float* mi_b1  = (const float*)d_in[5];
    const float* mi_w2  = (const float*)d_in[6];
    const float* mi_b2  = (const float*)d_in[7];
    const float* q_w    = (const float*)d_in[8];
    const float* k_w    = (const float*)d_in[9];
    const float* v_w    = (const float*)d_in[10];
    const float* mo_w1  = (const float*)d_in[11];
    const float* mo_b1  = (const float*)d_in[12];
    const float* mo_w2  = (const float*)d_in[13];
    const float* mo_b2  = (const float*)d_in[14];
    const float* n1_g   = (const float*)d_in[15];
    const float* n1_b   = (const float*)d_in[16];
    const float* n2_g   = (const float*)d_in[17];
    const float* n2_b   = (const float*)d_in[18];
    const float* e_w    = (const float*)d_in[19];
    const float* e_b    = (const float*)d_in[20];
    const float* f_w    = (const float*)d_in[21];
    const float* f_b    = (const float*)d_in[22];
    const float* g_w    = (const float*)d_in[23];
    const float* g_b    = (const float*)d_in[24];
    const float* h_w    = (const float*)d_in[25];
    const float* h_b    = (const float*)d_in[26];
    const float* fuse_w = (const float*)d_in[27];
    const float* fuse_b = (const float*)d_in[28];

    float* ws  = (float*)d_ws;
    float* out = (float*)d_out;

    k1_prep<<<dim3(72), 256, 0, stream>>>(
        front, back, bg, k_w, v_w, mi_w1, mi_b1, mi_w2, mi_b2, q_w,
        n1_g, n1_b, e_w, e_b, f_w, f_b, g_w, g_b, h_w, h_b, ws);

    size_t need128 = (size_t)(OFF_PART + 128*NPIX*4) * sizeof(float);
    if (ws_size >= need128){
        // primary: NC=128 (KPC=64): 1152 blocks, 18 waves/CU, ~39 MB ws
        k2_attn<64><<<dim3(NPIX/(256*8), 128), 256, 0, stream>>>(ws);
        k3_final<128><<<dim3(NPIX/256), 256, 0, stream>>>(
            ws, mo_w1, mo_b1, mo_w2, mo_b2, n2_g, n2_b, fuse_w, fuse_b, out);
    } else {
        // fallback: NC=64 (KPC=128): 576 blocks, ~20 MB ws
        k2_attn<128><<<dim3(NPIX/(256*8), 64), 256, 0, stream>>>(ws);
        k3_final<64><<<dim3(NPIX/256), 256, 0, stream>>>(
            ws, mo_w1, mo_b1, mo_w2, mo_b2, n2_g, n2_b, fuse_w, fuse_b, out);
    }
}